// Round 1
// 128.266 us; speedup vs baseline: 1.0355x; 1.0355x over previous
//
#include <hip/hip_runtime.h>

typedef __attribute__((ext_vector_type(8))) __bf16 bf16x8;
typedef __attribute__((ext_vector_type(4))) float f32x4;
typedef __attribute__((ext_vector_type(8))) unsigned short ushort8;

#define DSAMP 512
#define DIM   128
#define S1    ((size_t)16777216)   // one hi array: 128 b * 2 c * 512 r * 128 B (swizzled)
#define REG5  16384                // one staged region: 128 rows * 128 B
#define NBPB  36                   // kept for WS_NEEDED compatibility
#define NPAIR 18                   // paired tiles per batch (2 tiles per block)
#define NORM_OFF (2 * S1)
#define PART_OFF (2 * S1 + 524288)
#define WS_NEEDED (PART_OFF + (size_t)128 * NBPB * 4)

// ---------------------------------------------------------------------------
// Pass 1 v7: identical math to v6 (bf16-hi + exact fp32 norms), but the
// block->row mapping is XCD-aligned with pass 2: batch b is written by blocks
// with blockIdx%8 == b%8, so the consumer finds its data in the local L2.
// Within each XCD, batches are written in ascending bi; pass 2 consumes in
// DESCENDING bi so the freshest (least-evicted) batches are read first.
// ---------------------------------------------------------------------------
__global__ __launch_bounds__(256)
void presplit7(const float* __restrict__ x, const float* __restrict__ y,
               char* __restrict__ ws) {
    const int bid = blockIdx.x;           // 8192 blocks
    const int xcd = bid & 7;
    const int q   = bid >> 3;             // 0..1023
    const int bi  = q >> 6;               // 0..15 (batch seq within XCD)
    const int rem = q & 63;
    const int input = rem >> 5;           // 0=x, 1=y
    const int rg  = rem & 31;             // 16-row group within the cloud
    const int b   = xcd + 8 * bi;         // batch 0..127, b%8 == xcd

    const int tid = threadIdx.x;
    const int jb  = tid & 7;              // 16B block within chunk row
    const int c   = (tid >> 3) & 1;       // k-chunk 0/1
    const int rb  = rg * 16 + (tid >> 4); // row within cloud 0..511
    const int ri  = b * 512 + rb;         // global row 0..65535

    const float* src = (input ? y : x) + ((size_t)ri << 7) + c * 64 + jb * 8;
    float4 v0 = ((const float4*)src)[0];
    float4 v1 = ((const float4*)src)[1];

    // exact fp32 row norm (16 lanes per row, aligned group)
    float s = v0.x * v0.x + v0.y * v0.y + v0.z * v0.z + v0.w * v0.w
            + v1.x * v1.x + v1.y * v1.y + v1.z * v1.z + v1.w * v1.w;
    #pragma unroll
    for (int o = 8; o > 0; o >>= 1) s += __shfl_down(s, o, 16);

    float xs[8] = {v0.x, v0.y, v0.z, v0.w, v1.x, v1.y, v1.z, v1.w};
    ushort8 hv;
    #pragma unroll
    for (int e = 0; e < 8; ++e) {
        unsigned ub = __float_as_uint(xs[e]);
        hv[e] = (unsigned short)((ub + 0x7fffu + ((ub >> 16) & 1u)) >> 16);  // RNE
    }

    char* hi = ws + (size_t)input * S1;
    size_t off = ((size_t)(b * 2 + c) * 512 + rb) * 128
               + (size_t)((jb ^ (rb & 7)) * 16);
    *(ushort8*)(hi + off) = hv;

    if ((tid & 15) == 0) {
        float* nG = (float*)(ws + NORM_OFF) + (size_t)input * 65536;
        nG[ri] = s;
    }
}

// ---------------------------------------------------------------------------
// Pass 2 v10: paired tiles. Each block owns one A row-panel (staged once,
// both K-chunks, 32 KB) and computes TWO 128x128 tiles against it, staging
// each B chunk (16 KB) into a shared reuse buffer. The 36-tile triangle set
// (16 xy + 10 xx + 10 yy) is balanced into exactly 18 pairs per batch by
// computing some xy tiles transposed (A=y[j], B=x[i] — distance is symmetric).
// Grid = 128*18 = 2304 = 3.0 exact rounds at 3 blocks/CU. Tile-0 epilogue
// overlaps the tile-1 B-prefetch DMA.
// Diagonal sub-tile (needs i==j zeroing) is always pair slot 0.
// ---------------------------------------------------------------------------
__constant__ unsigned char T_Asrc[NPAIR]  = {0,0,0,0,0,0,0,0, 1,1,1,1,1,1,1,1,1,1};
__constant__ unsigned char T_Ai[NPAIR]    = {0,0,1,1,1,2,2,3, 0,0,0,0,1,1,1,2,2,3};
__constant__ unsigned char T_Bsrc0[NPAIR] = {0,0,0,0,1,0,1,0, 1,1,0,0,1,1,0,1,0,1};
__constant__ unsigned char T_Bsrc1[NPAIR] = {0,0,0,1,1,0,1,1, 1,1,0,0,1,0,0,1,0,0};
__constant__ unsigned char T_Bj0[NPAIR]   = {0,2,1,3,2,2,2,3, 0,2,0,2,1,3,2,2,0,3};
__constant__ unsigned char T_Bj1[NPAIR]   = {1,3,2,1,3,3,3,3, 1,3,1,3,2,0,3,3,3,0};
// weight codes: 0 -> +1.0 (xy), 1 -> -1.0 (xx/yy off-diag), 2 -> -0.5 (diag)
__constant__ char          T_wc0[NPAIR]   = {2,1,2,1,0,2,0,2, 2,1,0,0,2,1,0,2,0,2};
__constant__ char          T_wc1[NPAIR]   = {1,1,1,0,0,1,0,0, 1,1,0,0,1,0,0,1,0,0};
__constant__ unsigned char T_d0[NPAIR]    = {1,0,1,0,0,1,0,1, 1,0,0,0,1,0,0,1,0,1};

__global__ __launch_bounds__(256, 3)
void mmd_pair(const char* __restrict__ ws, float* __restrict__ partials) {
    __shared__ __align__(16) char smem[3 * REG5];   // A c0 | A c1 | B (49152 B)
    __shared__ float Pn[128];
    __shared__ float Qn0[128];
    __shared__ float Qn1[128];
    __shared__ float wred[4];

    const int tid  = threadIdx.x;
    const int bid  = blockIdx.x;
    const int xcd  = bid & 7;
    const int seq  = bid >> 3;            // 0..287
    const int s    = seq % NPAIR;
    const int bseq = seq / NPAIR;         // 0..15
    const int b    = xcd + 8 * (15 - bseq);  // reverse order: freshest L2 first

    const float* normX = (const float*)(ws + NORM_OFF);
    const float* normY = normX + 65536;

    const int Ai  = T_Ai[s];
    const int Bj0 = T_Bj0[s];
    const int Bj1 = T_Bj1[s];
    const char* Ap  = ws + (T_Asrc[s]  ? S1 : 0);
    const char* Bp0 = ws + (T_Bsrc0[s] ? S1 : 0);
    const char* Bp1 = ws + (T_Bsrc1[s] ? S1 : 0);
    const float* nA  = T_Asrc[s]  ? normY : normX;
    const float* nB0 = T_Bsrc0[s] ? normY : normX;
    const float* nB1 = T_Bsrc1[s] ? normY : normX;
    const int wc0 = T_wc0[s], wc1 = T_wc1[s];
    const float w0 = (wc0 == 0) ? 1.0f : ((wc0 == 1) ? -1.0f : -0.5f);
    const float w1 = (wc1 == 0) ? 1.0f : ((wc1 == 1) ? -1.0f : -0.5f);
    const bool dg0 = T_d0[s] != 0;

    if (tid < 128) {
        Pn[tid] = nA[(size_t)b * 512 + Ai * 128 + tid];
    } else {
        int qn = tid - 128;
        Qn0[qn] = nB0[(size_t)b * 512 + Bj0 * 128 + qn];
        Qn1[qn] = nB1[(size_t)b * 512 + Bj1 * 128 + qn];
    }

    const int lane    = tid & 63;
    const int wv      = tid >> 6;
    const int rowHalf = (wv >> 1) * 64;
    const int colHalf = (wv & 1) * 64;
    const int fm      = lane & 15;
    const int kq      = lane >> 4;
    const int sw      = fm & 7;

    const size_t ch0 = (size_t)(b * 2 + 0) * 512;
    const size_t ch1 = (size_t)(b * 2 + 1) * 512;

    // ---- stage A (both chunks, 32 KB) + B(tile0, chunk0) ----
    {
        const char* sA0 = Ap  + (ch0 + (size_t)Ai  * 128) * 128;
        const char* sA1 = Ap  + (ch1 + (size_t)Ai  * 128) * 128;
        const char* sB  = Bp0 + (ch0 + (size_t)Bj0 * 128) * 128;
        #pragma unroll
        for (int f = 0; f < 12; ++f) {
            int g = wv * 12 + f;                       // 0..47
            const char* base = (g < 16) ? sA0 : ((g < 32) ? sA1 : sB);
            const char* gs = base + (g & 15) * 1024 + lane * 16;
            char* ls = smem + (size_t)g * 1024 + lane * 16;
            __builtin_amdgcn_global_load_lds(
                (const __attribute__((address_space(1))) void*)gs,
                (__attribute__((address_space(3))) void*)ls, 16, 0, 0);
        }
    }

    auto stageB = [&](const char* Bp, int Bj, size_t ch) {
        const char* src = Bp + (ch + (size_t)Bj * 128) * 128;
        #pragma unroll
        for (int f = 0; f < 4; ++f) {
            int g = wv * 4 + f;                        // 0..15
            const char* gs = src + g * 1024 + lane * 16;
            char* ls = smem + 2 * REG5 + (size_t)g * 1024 + lane * 16;
            __builtin_amdgcn_global_load_lds(
                (const __attribute__((address_space(1))) void*)gs,
                (__attribute__((address_space(3))) void*)ls, 16, 0, 0);
        }
    };

    f32x4 acc[4][4];
    auto zero_acc = [&]() {
        #pragma unroll
        for (int a2 = 0; a2 < 4; ++a2)
            #pragma unroll
            for (int b2 = 0; b2 < 4; ++b2)
                acc[a2][b2] = (f32x4){0.f, 0.f, 0.f, 0.f};
    };

    auto compute = [&](int creg) {
        const char* Ab = smem + creg * REG5;
        const char* Bb = smem + 2 * REG5;
        #pragma unroll
        for (int ks = 0; ks < 2; ++ks) {
            const int jx = ((ks * 4 + kq) ^ sw) * 16;
            bf16x8 ah[4], bh[4];
            #pragma unroll
            for (int a2 = 0; a2 < 4; ++a2)
                ah[a2] = *(const bf16x8*)(Ab + (rowHalf + a2 * 16 + fm) * 128 + jx);
            #pragma unroll
            for (int b2 = 0; b2 < 4; ++b2)
                bh[b2] = *(const bf16x8*)(Bb + (colHalf + b2 * 16 + fm) * 128 + jx);
            #pragma unroll
            for (int a2 = 0; a2 < 4; ++a2)
                #pragma unroll
                for (int b2 = 0; b2 < 4; ++b2)
                    acc[a2][b2] = __builtin_amdgcn_mfma_f32_16x16x32_bf16(
                        ah[a2], bh[b2], acc[a2][b2], 0, 0, 0);
        }
    };

    auto tile_sum = [&](const float* Qn, bool dg) -> float {
        float Pr[16], Qc[4];
        #pragma unroll
        for (int a2 = 0; a2 < 4; ++a2)
            #pragma unroll
            for (int rg2 = 0; rg2 < 4; ++rg2)
                Pr[a2 * 4 + rg2] = Pn[rowHalf + a2 * 16 + kq * 4 + rg2];
        #pragma unroll
        for (int b2 = 0; b2 < 4; ++b2) Qc[b2] = Qn[colHalf + b2 * 16 + fm];
        float ls = 0.f;
        if (dg) {
            #pragma unroll
            for (int a2 = 0; a2 < 4; ++a2)
                #pragma unroll
                for (int b2 = 0; b2 < 4; ++b2)
                    #pragma unroll
                    for (int rg2 = 0; rg2 < 4; ++rg2) {
                        float d2 = fmaf(-2.0f, acc[a2][b2][rg2], Pr[a2 * 4 + rg2] + Qc[b2]);
                        float v  = __builtin_amdgcn_sqrtf(fmaxf(d2, 0.0f));
                        if ((rowHalf + a2 * 16 + kq * 4 + rg2) == (colHalf + b2 * 16 + fm)) v = 0.f;
                        ls += v;
                    }
        } else {
            #pragma unroll
            for (int a2 = 0; a2 < 4; ++a2)
                #pragma unroll
                for (int b2 = 0; b2 < 4; ++b2)
                    #pragma unroll
                    for (int rg2 = 0; rg2 < 4; ++rg2) {
                        float d2 = fmaf(-2.0f, acc[a2][b2][rg2], Pr[a2 * 4 + rg2] + Qc[b2]);
                        ls += __builtin_amdgcn_sqrtf(fmaxf(d2, 0.0f));
                    }
        }
        return ls;
    };

    // ---- tile 0 ----
    zero_acc();
    __syncthreads();                 // A+B(t0,c0) staged
    compute(0);
    __syncthreads();                 // Bbuf free
    stageB(Bp0, Bj0, ch1);
    __syncthreads();                 // B(t0,c1) staged
    compute(1);
    __syncthreads();                 // Bbuf free
    stageB(Bp1, Bj1, ch0);           // tile-1 prefetch in flight...
    float lsum = w0 * tile_sum(Qn0, dg0);   // ...hidden under epilogue VALU
    __syncthreads();                 // B(t1,c0) staged

    // ---- tile 1 ----
    zero_acc();
    compute(0);
    __syncthreads();                 // Bbuf free
    stageB(Bp1, Bj1, ch1);
    __syncthreads();                 // B(t1,c1) staged
    compute(1);
    lsum += w1 * tile_sum(Qn1, false);

    #pragma unroll
    for (int off = 32; off > 0; off >>= 1) lsum += __shfl_down(lsum, off, 64);
    if (lane == 0) wred[wv] = lsum;
    __syncthreads();
    if (tid == 0)
        partials[bid] = wred[0] + wred[1] + wred[2] + wred[3];
}

// ---------------------------------------------------------------------------
// Fallback (in-kernel 3-term conversion, full 48 tiles/batch) if ws too small.
// ---------------------------------------------------------------------------
__global__ __launch_bounds__(256, 2)
void mmd_tile_fallback(const float* __restrict__ x, const float* __restrict__ y,
                       float* __restrict__ partials) {
    __shared__ __align__(16) char smem[4 * 128 * 144];
    __shared__ float Pn[128];
    __shared__ float Qn[128];
    __shared__ float wred[4];

    char* Ah = smem;
    char* Al = smem + 1 * 128 * 144;
    char* Bh = smem + 2 * 128 * 144;
    char* Bl = smem + 3 * 128 * 144;

    const int tid  = threadIdx.x;
    const int bid  = blockIdx.x;
    const int tj   = bid & 3;
    const int ti   = (bid >> 2) & 3;
    const int type = (bid >> 4) % 3;
    const int b    = bid / 48;

    const float* Xb = x + (size_t)b * DSAMP * DIM;
    const float* Yb = y + (size_t)b * DSAMP * DIM;
    const float* Pp; const float* Qp; float w;
    if (type == 0)      { Pp = Xb; Qp = Yb; w = 1.0f;  }
    else if (type == 1) { Pp = Xb; Qp = Xb; w = -0.5f; }
    else                { Pp = Yb; Qp = Yb; w = -0.5f; }
    Pp += (size_t)ti * 128 * DIM;
    Qp += (size_t)tj * 128 * DIM;

    {
        const float* rp = (tid < 128) ? (Pp + (size_t)tid * DIM)
                                      : (Qp + (size_t)(tid - 128) * DIM);
        float s = 0.f;
        #pragma unroll
        for (int k4 = 0; k4 < 32; ++k4) {
            float4 v = ((const float4*)rp)[k4];
            s += v.x * v.x + v.y * v.y + v.z * v.z + v.w * v.w;
        }
        if (tid < 128) Pn[tid] = s; else Qn[tid - 128] = s;
    }

    const int lane    = tid & 63;
    const int wv      = tid >> 6;
    const int rowHalf = (wv >> 1) * 64;
    const int colHalf = (wv & 1) * 64;
    const int fm      = lane & 15;
    const int kq      = lane >> 4;

    f32x4 acc[4][4];
    #pragma unroll
    for (int a2 = 0; a2 < 4; ++a2)
        #pragma unroll
        for (int b2 = 0; b2 < 4; ++b2)
            acc[a2][b2] = (f32x4){0.f, 0.f, 0.f, 0.f};

    for (int c = 0; c < 2; ++c) {
        if (c) __syncthreads();
        #pragma unroll
        for (int side = 0; side < 2; ++side) {
            const float* sp = side ? Qp : Pp;
            char* dh = side ? Bh : Ah;
            char* dl = side ? Bl : Al;
            #pragma unroll
            for (int it = 0; it < 4; ++it) {
                int u  = it * 256 + tid;
                int r  = u >> 3;
                int c8 = u & 7;
                const float* g = sp + (size_t)r * DIM + c * 64 + c8 * 8;
                float4 v0 = ((const float4*)g)[0];
                float4 v1 = ((const float4*)g)[1];
                float xs[8] = {v0.x, v0.y, v0.z, v0.w, v1.x, v1.y, v1.z, v1.w};
                ushort8 hv, lv;
                #pragma unroll
                for (int e = 0; e < 8; ++e) {
                    float xv = xs[e];
                    unsigned ub = __float_as_uint(xv);
                    unsigned hr = (ub + 0x7fffu + ((ub >> 16) & 1u)) >> 16;
                    float hf = __uint_as_float(hr << 16);
                    float rs = xv - hf;
                    unsigned ul = __float_as_uint(rs);
                    unsigned lr = (ul + 0x7fffu + ((ul >> 16) & 1u)) >> 16;
                    hv[e] = (unsigned short)hr;
                    lv[e] = (unsigned short)lr;
                }
                *(ushort8*)(dh + r * 144 + c8 * 16) = hv;
                *(ushort8*)(dl + r * 144 + c8 * 16) = lv;
            }
        }
        __syncthreads();
        #pragma unroll
        for (int ks = 0; ks < 2; ++ks) {
            const int kb2 = (ks * 32 + kq * 8) * 2;
            bf16x8 ah[4], al[4], bh[4], bl[4];
            #pragma unroll
            for (int a2 = 0; a2 < 4; ++a2) {
                int ar = rowHalf + a2 * 16 + fm;
                ah[a2] = *(const bf16x8*)(Ah + ar * 144 + kb2);
                al[a2] = *(const bf16x8*)(Al + ar * 144 + kb2);
            }
            #pragma unroll
            for (int b2 = 0; b2 < 4; ++b2) {
                int br = colHalf + b2 * 16 + fm;
                bh[b2] = *(const bf16x8*)(Bh + br * 144 + kb2);
                bl[b2] = *(const bf16x8*)(Bl + br * 144 + kb2);
            }
            #pragma unroll
            for (int a2 = 0; a2 < 4; ++a2)
                #pragma unroll
                for (int b2 = 0; b2 < 4; ++b2) {
                    acc[a2][b2] = __builtin_amdgcn_mfma_f32_16x16x32_bf16(ah[a2], bh[b2], acc[a2][b2], 0, 0, 0);
                    acc[a2][b2] = __builtin_amdgcn_mfma_f32_16x16x32_bf16(ah[a2], bl[b2], acc[a2][b2], 0, 0, 0);
                    acc[a2][b2] = __builtin_amdgcn_mfma_f32_16x16x32_bf16(al[a2], bh[b2], acc[a2][b2], 0, 0, 0);
                }
        }
    }

    const bool selfm = (type != 0) && (ti == tj);
    float lsum = 0.f;
    #pragma unroll
    for (int a2 = 0; a2 < 4; ++a2) {
        int ib = rowHalf + a2 * 16 + kq * 4;
        #pragma unroll
        for (int b2 = 0; b2 < 4; ++b2) {
            int j = colHalf + b2 * 16 + fm;
            float qn = Qn[j];
            #pragma unroll
            for (int rg = 0; rg < 4; ++rg) {
                int i = ib + rg;
                float d2 = Pn[i] + qn - 2.0f * acc[a2][b2][rg];
                if (d2 > 0.f && !(selfm && i == j)) lsum += sqrtf(d2);
            }
        }
    }
    #pragma unroll
    for (int off = 32; off > 0; off >>= 1) lsum += __shfl_down(lsum, off, 64);
    if (lane == 0) wred[wv] = lsum;
    __syncthreads();
    if (tid == 0)
        partials[bid] = (wred[0] + wred[1] + wred[2] + wred[3]) * w;
}

__global__ __launch_bounds__(256)
void mmd_finalize_kernel(const float* __restrict__ partials, int n,
                         float* __restrict__ out, double scale) {
    __shared__ double sh[256];
    double s = 0.0;
    for (int i = threadIdx.x; i < n; i += 256) s += (double)partials[i];
    sh[threadIdx.x] = s;
    __syncthreads();
    for (int off = 128; off > 0; off >>= 1) {
        if ((int)threadIdx.x < off) sh[threadIdx.x] += sh[threadIdx.x + off];
        __syncthreads();
    }
    if (threadIdx.x == 0) out[0] = (float)(sh[0] * scale);
}

extern "C" void kernel_launch(void* const* d_in, const int* in_sizes, int n_in,
                              void* d_out, int out_size, void* d_ws, size_t ws_size,
                              hipStream_t stream) {
    const float* x = (const float*)d_in[0];
    const float* y = (const float*)d_in[1];
    float* out = (float*)d_out;

    const int n = in_sizes[0];
    const int B = n / (DSAMP * DIM);       // 128
    const double scale = 1.0 / ((double)B * (double)DSAMP * (double)DSAMP);

    if (ws_size >= WS_NEEDED && B == 128) {
        char* ws = (char*)d_ws;
        float* partials = (float*)(ws + PART_OFF);
        const int nblocks = B * NPAIR;     // 2304 = 3.0 exact rounds @ 3 blk/CU
        presplit7<<<dim3(8192), dim3(256), 0, stream>>>(x, y, ws);
        mmd_pair<<<dim3(nblocks), dim3(256), 0, stream>>>(ws, partials);
        mmd_finalize_kernel<<<dim3(1), dim3(256), 0, stream>>>(partials, nblocks, out, scale);
    } else {
        float* partials = (float*)d_ws;
        const int nblocks = B * 48;
        mmd_tile_fallback<<<dim3(nblocks), dim3(256), 0, stream>>>(x, y, partials);
        mmd_finalize_kernel<<<dim3(1), dim3(256), 0, stream>>>(partials, nblocks, out, scale);
    }
}